// Round 2
// baseline (668.457 us; speedup 1.0000x reference)
//
#include <hip/hip_runtime.h>

// SupConLoss on MI355X. features: [4096, 2, 128] fp32; labels: [4096] int; out: 1 f32.
//
// R8 changes vs R7:
//  - Single persistent kernel (grid 1024 x 256 = exactly co-resident: 35.5 KB
//    LDS -> 4 blocks/CU, VGPR<=128 via __launch_bounds__(256,4)), with
//    device-scope ticket barriers between phases:
//      phase A: normalize (blocks 0..1022) + zero accumulators (blocks 0..32)
//               + label bucketing (block 1023, concurrent)
//      phase B: negsum, segments grid-strided (1056 segs over 1024 blocks)
//      phase C: loss, blocks 0..99 (one class each), others exit
//  - Loss phase reads MFMA fragments DIRECTLY from L2-resident nf (no 48 KB
//    LDS staging -- that would break 4-blocks/CU co-residency). A-tile halved
//    (rs=2) to stay within 128 VGPR.
//  - Barrier counters zeroed by an 8-byte hipMemsetAsync before the kernel
//    (graph-capturable; does not rely on harness poison semantics).
//
// ws layout: nf (2 MB) | neg_sum 8192 f32 | total f32 | done u32 | counts 100
//            | offsets 101 | classIdx 4096 | bar[2] u32

#define BATCH 4096
#define NN    8192
#define DD    128
#define NCLS  100
#define MAXR  192
#define NB    64
#define SEG   2
#define NSEG  1056        // sum_{bi=0}^{63} ceil((64-bi)/2)
#define GRID  1024
#define SCALE (1.0f / 0.07f)

typedef __attribute__((ext_vector_type(8))) short bf16x8;
typedef __attribute__((ext_vector_type(4))) float f32x4;

__device__ __forceinline__ unsigned short f2bf(float f) {
    unsigned u = __float_as_uint(f);
    u += 0x7FFF + ((u >> 16) & 1);
    return (unsigned short)(u >> 16);
}

__device__ __forceinline__ void gridbar(unsigned* ctr, unsigned target) {
    __syncthreads();
    if (threadIdx.x == 0) {
        __threadfence();
        __hip_atomic_fetch_add(ctr, 1u, __ATOMIC_RELEASE, __HIP_MEMORY_SCOPE_AGENT);
        while (__hip_atomic_load(ctr, __ATOMIC_ACQUIRE, __HIP_MEMORY_SCOPE_AGENT) < target)
            __builtin_amdgcn_s_sleep(2);
    }
    __syncthreads();
}

__device__ __forceinline__ void norm_row(const float* feat, unsigned short* nf,
                                         int row, int lane) {
    int v = row >> 12, b = row & (BATCH - 1);
    const float2* src = (const float2*)(feat + ((size_t)b * 2 + v) * DD);
    float2 x = src[lane];
    float ss = x.x * x.x + x.y * x.y;
    #pragma unroll
    for (int m = 32; m >= 1; m >>= 1) ss += __shfl_xor(ss, m, 64);
    float inv = rsqrtf(ss);
    ushort2 o;
    o.x = f2bf(x.x * inv);
    o.y = f2bf(x.y * inv);
    ((ushort2*)(nf + (size_t)row * DD))[lane] = o;
}

// stage one 64-row x 128-col bf16 half-tile into LDS buffer `buf` (16 KB),
// XOR-swizzled: LDS slot (r, cS) holds global chunk (r, cS ^ (r&15)).
__device__ __forceinline__ void stage_half(unsigned short* smem, const unsigned short* nf,
                                           int buf, int hrow, int wave, int lane) {
    #pragma unroll
    for (int it = 0; it < 4; ++it) {
        int widx = wave * 4 + it;              // 0..15
        int chunkIdx = widx * 64 + lane;       // 0..1023
        int r = chunkIdx >> 4, cS = chunkIdx & 15;
        int cG = cS ^ (r & 15);
        const unsigned short* gp = nf + (size_t)(hrow + r) * DD + cG * 8;
        unsigned short* lp = smem + (size_t)buf * 8192 + (size_t)widx * 512;
        __builtin_amdgcn_global_load_lds(
            (const __attribute__((address_space(1))) void*)gp,
            (__attribute__((address_space(3))) void*)lp, 16, 0, 0);
    }
}

// one negsum segment: column block-pairs (bi, bj0..bj0+nt-1), 128x128 tiles
__device__ void negsum_seg(int g, unsigned short* smem,
                           const unsigned short* nf, const int* labels,
                           float* neg_sum, int wave, int lane) {
    int bi = 0;
    for (;;) {
        int n = (NB - bi + SEG - 1) / SEG;
        if (g < n) break;
        g -= n; ++bi;
    }
    int bj0 = bi + g * SEG;
    int nt = NB - bj0; if (nt > SEG) nt = SEG;
    int nht = nt * 2;

    int q = lane >> 4, nq = lane & 15;
    int rowW = bi * 128 + wave * 32;           // wave's 32-row base
    const bf16x8* nfv = (const bf16x8*)nf;

    bf16x8 aF[2][4];
    #pragma unroll
    for (int rs = 0; rs < 2; ++rs) {
        int r = rowW + rs * 16 + nq;
        #pragma unroll
        for (int s = 0; s < 4; ++s) aF[rs][s] = nfv[r * 16 + s * 4 + q];
    }
    int rlab[2][4];
    float rowsum[2][4];
    #pragma unroll
    for (int rs = 0; rs < 2; ++rs)
        #pragma unroll
        for (int rr = 0; rr < 4; ++rr) {
            rlab[rs][rr] = labels[(rowW + rs * 16 + q * 4 + rr) & (BATCH - 1)];
            rowsum[rs][rr] = 0.0f;
        }

    stage_half(smem, nf, 0, bj0 * 128, wave, lane);

    for (int ht = 0; ht < nht; ++ht) {
        __syncthreads();                       // buf ht&1 ready
        if (ht + 1 < nht) stage_half(smem, nf, (ht + 1) & 1, bj0 * 128 + (ht + 1) * 64, wave, lane);
        int bj = bj0 + (ht >> 1);
        bool diag = (bj == bi);
        const char* sB = (const char*)(smem + (size_t)(ht & 1) * 8192);

        f32x4 acc[2][4];
        #pragma unroll
        for (int rs = 0; rs < 2; ++rs)
            #pragma unroll
            for (int cs = 0; cs < 4; ++cs) acc[rs][cs] = (f32x4){0.f, 0.f, 0.f, 0.f};
        #pragma unroll
        for (int s = 0; s < 4; ++s) {
            bf16x8 bF[4];
            #pragma unroll
            for (int cs = 0; cs < 4; ++cs) {
                int rB = cs * 16 + nq;                       // local row in half-tile
                int slot = rB * 16 + ((s * 4 + q) ^ nq);
                bF[cs] = *(const bf16x8*)(sB + slot * 16);
            }
            #pragma unroll
            for (int rs = 0; rs < 2; ++rs)
                #pragma unroll
                for (int cs = 0; cs < 4; ++cs)
                    acc[rs][cs] = __builtin_amdgcn_mfma_f32_16x16x32_bf16(
                        aF[rs][s], bF[cs], acc[rs][cs], 0, 0, 0);
        }

        int colBase = bj0 * 128 + ht * 64;
        // C/D layout: col = lane&15, row = (lane>>4)*4 + reg
        #pragma unroll
        for (int cs = 0; cs < 4; ++cs) {
            int col = colBase + cs * 16 + nq;
            int cl = labels[col & (BATCH - 1)];
            float colsum = 0.0f;
            #pragma unroll
            for (int rs = 0; rs < 2; ++rs)
                #pragma unroll
                for (int rr = 0; rr < 4; ++rr) {
                    float e = __expf(acc[rs][cs][rr] * SCALE);
                    float ev = (rlab[rs][rr] != cl) ? e : 0.0f;
                    rowsum[rs][rr] += ev;
                    colsum += ev;
                }
            if (!diag) {
                colsum += __shfl_xor(colsum, 16, 64);
                colsum += __shfl_xor(colsum, 32, 64);
                if (q == 0) atomicAdd(&neg_sum[col], colsum);
            }
        }
    }

    #pragma unroll
    for (int rs = 0; rs < 2; ++rs)
        #pragma unroll
        for (int rr = 0; rr < 4; ++rr) {
            float vsum = rowsum[rs][rr];
            vsum += __shfl_xor(vsum, 1, 64);
            vsum += __shfl_xor(vsum, 2, 64);
            vsum += __shfl_xor(vsum, 4, 64);
            vsum += __shfl_xor(vsum, 8, 64);
            if (nq == 0) atomicAdd(&neg_sum[rowW + rs * 16 + q * 4 + rr], vsum);
        }
}

__global__ __launch_bounds__(256, 4) void k_fused(
        const float* __restrict__ feat, const int* __restrict__ labels,
        unsigned short* __restrict__ nf, float* __restrict__ neg_sum,
        float* __restrict__ total, unsigned* __restrict__ done,
        int* __restrict__ counts, int* __restrict__ offsets,
        int* __restrict__ classIdx, unsigned* __restrict__ bar,
        float* __restrict__ out) {
    __shared__ __attribute__((aligned(16))) unsigned short smem[2 * 64 * 128];  // 32 KB
    __shared__ int cnt[NCLS], off[NCLS], cur[NCLS];
    __shared__ int s_rows[MAXR];
    __shared__ float s_ns[MAXR];
    __shared__ float red[4];

    int blk = blockIdx.x;
    int tid = threadIdx.x, wave = tid >> 6, lane = tid & 63;

    // ---------------- phase A: normalize + zero + bucket ----------------
    if (blk < GRID - 1) {
        int gi = blk * 256 + tid;
        if (gi < NN + 2) ((float*)neg_sum)[gi] = 0.0f;   // neg_sum, total, done
        int wv = blk * 4 + wave;                          // 0..4091
        norm_row(feat, nf, wv, lane);
        norm_row(feat, nf, wv + 4092, lane);
        if (wv < 8) norm_row(feat, nf, 8184 + wv, lane);
    } else {
        // bucket path (256 threads)
        if (tid < NCLS) cnt[tid] = 0;
        __syncthreads();
        for (int b = tid; b < BATCH; b += 256) atomicAdd(&cnt[labels[b]], 1);
        __syncthreads();
        if (tid < NCLS) {
            int a = 0;
            for (int k = 0; k < tid; ++k) a += cnt[k];   // lockstep LDS broadcast
            off[tid] = a;
            cur[tid] = 0;
            counts[tid] = cnt[tid];
            offsets[tid] = a;
        }
        if (tid == 0) offsets[NCLS] = BATCH;
        __syncthreads();
        for (int b = tid; b < BATCH; b += 256) {
            int l = labels[b];
            int p = atomicAdd(&cur[l], 1);
            classIdx[off[l] + p] = b;
        }
    }

    gridbar(&bar[0], GRID);

    // ---------------- phase B: negsum (1056 segments over 1024 blocks) ----------------
    negsum_seg(blk, smem, nf, labels, neg_sum, wave, lane);
    if (blk < NSEG - GRID) negsum_seg(blk + GRID, smem, nf, labels, neg_sum, wave, lane);

    gridbar(&bar[1], GRID);

    // ---------------- phase C: loss (blocks 0..99, one class each) ----------------
    if (blk >= NCLS) return;
    int c = blk;
    int m = counts[c], offc = offsets[c];
    int twoM = 2 * m; if (twoM > MAXR) twoM = MAXR;
    int q = lane >> 4, nq = lane & 15;

    for (int r = tid; r < twoM; r += 256) {
        int b = classIdx[offc + (r < m ? r : r - m)];
        int row = (r < m) ? b : b + BATCH;
        s_rows[r] = row;
        s_ns[r] = neg_sum[row];
    }
    __syncthreads();

    const bf16x8* nfv = (const bf16x8*)nf;
    float partial = 0.0f;
    int nt32 = (twoM + 31) >> 5;             // A tiles of 32 rows
    int nt64 = (twoM + 63) >> 6;             // B tiles of 64 cols
    int npairs = nt32 * nt64;
    for (int pp = wave; pp < npairs; pp += 4) {
        int ti = pp / nt64, tj = pp - ti * nt64;
        // A frags: rows ti*32 .. +31, direct from L2-resident nf (gathered)
        bf16x8 aF[2][4];
        #pragma unroll
        for (int rs = 0; rs < 2; ++rs) {
            int rA = ti * 32 + rs * 16 + nq;
            int rAc = rA < twoM ? rA : twoM - 1;
            int grow = s_rows[rAc];
            #pragma unroll
            for (int s = 0; s < 4; ++s) aF[rs][s] = nfv[grow * 16 + s * 4 + q];
        }
        f32x4 acc[2][4];
        #pragma unroll
        for (int rs = 0; rs < 2; ++rs)
            #pragma unroll
            for (int cs = 0; cs < 4; ++cs) acc[rs][cs] = (f32x4){0.f, 0.f, 0.f, 0.f};
        #pragma unroll
        for (int s = 0; s < 4; ++s) {
            bf16x8 bF[4];
            #pragma unroll
            for (int cs = 0; cs < 4; ++cs) {
                int rB = tj * 64 + cs * 16 + nq;
                int rBc = rB < twoM ? rB : twoM - 1;
                bF[cs] = nfv[s_rows[rBc] * 16 + s * 4 + q];
            }
            #pragma unroll
            for (int rs = 0; rs < 2; ++rs)
                #pragma unroll
                for (int cs = 0; cs < 4; ++cs)
                    acc[rs][cs] = __builtin_amdgcn_mfma_f32_16x16x32_bf16(
                        aF[rs][s], bF[cs], acc[rs][cs], 0, 0, 0);
        }
        #pragma unroll
        for (int cs = 0; cs < 4; ++cs) {
            int qq = tj * 64 + cs * 16 + nq;
            float ns = s_ns[qq < twoM ? qq : 0];
            #pragma unroll
            for (int rs = 0; rs < 2; ++rs)
                #pragma unroll
                for (int rr = 0; rr < 4; ++rr) {
                    int p = ti * 32 + rs * 16 + q * 4 + rr;
                    bool valid = (p < twoM) && (qq < twoM) && (p != qq);
                    float logit = acc[rs][cs][rr] * SCALE;
                    float term = logit - __logf(ns + __expf(logit));
                    partial += valid ? term : 0.0f;
                }
        }
    }
    #pragma unroll
    for (int mm = 32; mm >= 1; mm >>= 1) partial += __shfl_xor(partial, mm, 64);
    if (lane == 0) red[wave] = partial;
    __syncthreads();
    if (tid == 0) {
        atomicAdd(total, red[0] + red[1] + red[2] + red[3]);
        __threadfence();
        unsigned prev = __hip_atomic_fetch_add(done, 1u, __ATOMIC_ACQ_REL,
                                               __HIP_MEMORY_SCOPE_AGENT);
        if (prev == (unsigned)(NCLS - 1)) {
            float tot = __hip_atomic_load(total, __ATOMIC_ACQUIRE,
                                          __HIP_MEMORY_SCOPE_AGENT);
            out[0] = -tot * (1.0f / (float)NN);
        }
    }
}

extern "C" void kernel_launch(void* const* d_in, const int* in_sizes, int n_in,
                              void* d_out, int out_size, void* d_ws, size_t ws_size,
                              hipStream_t stream) {
    const float* feat = (const float*)d_in[0];
    const int* labels = (const int*)d_in[1];
    unsigned short* nf = (unsigned short*)d_ws;
    float* neg_sum = (float*)((char*)d_ws + (size_t)NN * DD * sizeof(unsigned short));
    float* total    = neg_sum + NN;           // 1
    unsigned* done  = (unsigned*)(total + 1); // 1
    int* counts     = (int*)(done + 1);       // 100
    int* offsets    = counts + NCLS;          // 101
    int* classIdx   = offsets + NCLS + 1;     // 4096
    unsigned* bar   = (unsigned*)(classIdx + BATCH);  // 2
    float* out = (float*)d_out;

    hipMemsetAsync(bar, 0, 2 * sizeof(unsigned), stream);
    hipLaunchKernelGGL(k_fused, dim3(GRID), dim3(256), 0, stream,
                       feat, labels, nf, neg_sum, total, done,
                       counts, offsets, classIdx, bar, out);
}

// Round 3
// 105.741 us; speedup vs baseline: 6.3216x; 6.3216x over previous
//
#include <hip/hip_runtime.h>

// SupConLoss on MI355X. features: [4096, 2, 128] fp32; labels: [4096] int; out: 1 f32.
//
// R9 changes vs R8 (which regressed 6x and is reverted):
//  - Back to the R7 three-kernel skeleton (norm+bucket, negsum, loss).
//    R8's agent-scope spin barrier caused an L2-invalidate storm (649 us,
//    VALUBusy 2.2%): never spin on agent-scope acquire loads on gfx950.
//  - k_negsum rebuilt ATOMIC-FREE: drop the symmetric decomposition
//    (recompute both triangles, +4 us MFMA), each block owns a 128-row x
//    1024-col strip; row sums accumulate in registers and are PLAIN-STORED
//    to neg_part[8][8192]. Eliminates ~300K device-scope atomicAdds (each a
//    serialized fabric RMW past the non-coherent L2s) -- the leading suspect
//    for the ~80 us of non-arithmetic time (R8 counters: real compute only
//    ~20 us; R6->R7 proved launch gaps small).
//  - neg_part needs no zeroing (each slot written exactly once); only
//    total/done are zeroed (block 0 of norm kernel).
//  - k_loss: s_ns[row] = sum of 8 partials; otherwise R7's staged version.
//  - Column labels staged once per negsum block into LDS (s_clab, 4 KB).
//
// ws layout: nf (2 MB) | neg_part 8x8192 f32 (256 KB) | total f32 | done u32
//            | counts 100 | offsets 101 | classIdx 4096

#define BATCH 4096
#define NN    8192
#define DD    128
#define NCLS  100
#define MAXR  192
#define NCHUNK  8         // column chunks of 1024
#define CHTILES 16        // 64-col half-tiles per chunk
#define SCALE (1.0f / 0.07f)

typedef __attribute__((ext_vector_type(8))) short bf16x8;
typedef __attribute__((ext_vector_type(4))) float f32x4;

__device__ __forceinline__ unsigned short f2bf(float f) {
    unsigned u = __float_as_uint(f);
    u += 0x7FFF + ((u >> 16) & 1);
    return (unsigned short)(u >> 16);
}

// blocks 0..2047: normalize; block 0 also zeroes total/done
// block 2048:     label bucketing (histogram, offsets, member scatter)
__global__ __launch_bounds__(256) void k_norm_bucket(
        const float* __restrict__ feat, unsigned short* __restrict__ nf,
        unsigned* __restrict__ zeroTD,
        const int* __restrict__ labels, int* __restrict__ counts,
        int* __restrict__ offsets, int* __restrict__ classIdx) {
    __shared__ int cnt[NCLS], off[NCLS], cur[NCLS];

    if (blockIdx.x < NN / 4) {
        if (blockIdx.x == 0 && threadIdx.x < 2) zeroTD[threadIdx.x] = 0u;  // total, done
        int wave = threadIdx.x >> 6, lane = threadIdx.x & 63;
        int row = blockIdx.x * 4 + wave;
        int v = row >> 12, b = row & (BATCH - 1);
        const float2* src = (const float2*)(feat + ((size_t)b * 2 + v) * DD);
        float2 x = src[lane];
        float ss = x.x * x.x + x.y * x.y;
        #pragma unroll
        for (int m = 32; m >= 1; m >>= 1) ss += __shfl_xor(ss, m, 64);
        float inv = rsqrtf(ss);
        ushort2 o;
        o.x = f2bf(x.x * inv);
        o.y = f2bf(x.y * inv);
        ((ushort2*)(nf + (size_t)row * DD))[lane] = o;
        return;
    }

    // ---- bucket path (single block, 256 threads) ----
    int tid = threadIdx.x;
    if (tid < NCLS) cnt[tid] = 0;
    __syncthreads();
    for (int b = tid; b < BATCH; b += 256) atomicAdd(&cnt[labels[b]], 1);
    __syncthreads();
    if (tid < NCLS) {
        int a = 0;
        for (int k = 0; k < tid; ++k) a += cnt[k];   // lockstep LDS broadcast
        off[tid] = a;
        cur[tid] = 0;
        counts[tid] = cnt[tid];
        offsets[tid] = a;
    }
    if (tid == 0) offsets[NCLS] = BATCH;
    __syncthreads();
    for (int b = tid; b < BATCH; b += 256) {
        int l = labels[b];
        int p = atomicAdd(&cur[l], 1);
        classIdx[off[l] + p] = b;
    }
}

// stage one 64-row x 128-col bf16 half-tile into LDS buffer `buf` (16 KB),
// XOR-swizzled: LDS slot (r, cS) holds global chunk (r, cS ^ (r&15)).
__device__ __forceinline__ void stage_half(unsigned short* smem, const unsigned short* nf,
                                           int buf, int hrow, int wave, int lane) {
    #pragma unroll
    for (int it = 0; it < 4; ++it) {
        int widx = wave * 4 + it;              // 0..15
        int chunkIdx = widx * 64 + lane;       // 0..1023
        int r = chunkIdx >> 4, cS = chunkIdx & 15;
        int cG = cS ^ (r & 15);
        const unsigned short* gp = nf + (size_t)(hrow + r) * DD + cG * 8;
        unsigned short* lp = smem + (size_t)buf * 8192 + (size_t)widx * 512;
        __builtin_amdgcn_global_load_lds(
            (const __attribute__((address_space(1))) void*)gp,
            (__attribute__((address_space(3))) void*)lp, 16, 0, 0);
    }
}

// ---- pass 1 (atomic-free): block (bi, ch) computes, for its 128 rows,
// sum_j exp(logit)*negmask over cols [ch*1024, +1024), plain-stores the
// partial to neg_part[ch][row]. ----
__global__ __launch_bounds__(256, 4) void k_negsum(
        const unsigned short* __restrict__ nf,
        const int* __restrict__ labels,
        float* __restrict__ neg_part) {
    __shared__ __attribute__((aligned(16))) unsigned short smem[2 * 64 * 128];  // 32 KB
    __shared__ int s_clab[1024];                                                // 4 KB

    int blk = blockIdx.x;
    int bi = blk >> 3;          // 0..63  row block (128 rows)
    int ch = blk & 7;           // 0..7   column chunk (1024 cols)
    int colBase0 = ch * 1024;

    int tid = threadIdx.x, wave = tid >> 6, lane = tid & 63;
    int q = lane >> 4, nq = lane & 15;
    int rowW = bi * 128 + wave * 32;           // wave's 32-row base
    const bf16x8* nfv = (const bf16x8*)nf;

    // column labels for the whole chunk, once
    for (int i = tid; i < 1024; i += 256)
        s_clab[i] = labels[(colBase0 + i) & (BATCH - 1)];

    // A frags (8): direct global, once per block
    bf16x8 aF[2][4];
    #pragma unroll
    for (int rs = 0; rs < 2; ++rs) {
        int r = rowW + rs * 16 + nq;
        #pragma unroll
        for (int s = 0; s < 4; ++s) aF[rs][s] = nfv[r * 16 + s * 4 + q];
    }
    int rlab[2][4];
    float rowsum[2][4];
    #pragma unroll
    for (int rs = 0; rs < 2; ++rs)
        #pragma unroll
        for (int rr = 0; rr < 4; ++rr) {
            rlab[rs][rr] = labels[(rowW + rs * 16 + q * 4 + rr) & (BATCH - 1)];
            rowsum[rs][rr] = 0.0f;
        }

    stage_half(smem, nf, 0, colBase0, wave, lane);

    for (int ht = 0; ht < CHTILES; ++ht) {
        __syncthreads();                       // buf ht&1 ready (also covers s_clab)
        if (ht + 1 < CHTILES) stage_half(smem, nf, (ht + 1) & 1, colBase0 + (ht + 1) * 64, wave, lane);
        const char* sB = (const char*)(smem + (size_t)(ht & 1) * 8192);

        f32x4 acc[2][4];
        #pragma unroll
        for (int rs = 0; rs < 2; ++rs)
            #pragma unroll
            for (int cs = 0; cs < 4; ++cs) acc[rs][cs] = (f32x4){0.f, 0.f, 0.f, 0.f};
        #pragma unroll
        for (int s = 0; s < 4; ++s) {
            bf16x8 bF[4];
            #pragma unroll
            for (int cs = 0; cs < 4; ++cs) {
                int rB = cs * 16 + nq;                       // local row in half-tile
                int slot = rB * 16 + ((s * 4 + q) ^ nq);
                bF[cs] = *(const bf16x8*)(sB + slot * 16);
            }
            #pragma unroll
            for (int rs = 0; rs < 2; ++rs)
                #pragma unroll
                for (int cs = 0; cs < 4; ++cs)
                    acc[rs][cs] = __builtin_amdgcn_mfma_f32_16x16x32_bf16(
                        aF[rs][s], bF[cs], acc[rs][cs], 0, 0, 0);
        }

        // C/D layout: col = lane&15, row = (lane>>4)*4 + reg
        #pragma unroll
        for (int cs = 0; cs < 4; ++cs) {
            int cl = s_clab[ht * 64 + cs * 16 + nq];
            #pragma unroll
            for (int rs = 0; rs < 2; ++rs)
                #pragma unroll
                for (int rr = 0; rr < 4; ++rr) {
                    float e = __expf(acc[rs][cs][rr] * SCALE);
                    rowsum[rs][rr] += (rlab[rs][rr] != cl) ? e : 0.0f;
                }
        }
    }

    // reduce over nq (col groups) and plain-store the partial
    #pragma unroll
    for (int rs = 0; rs < 2; ++rs)
        #pragma unroll
        for (int rr = 0; rr < 4; ++rr) {
            float vsum = rowsum[rs][rr];
            vsum += __shfl_xor(vsum, 1, 64);
            vsum += __shfl_xor(vsum, 2, 64);
            vsum += __shfl_xor(vsum, 4, 64);
            vsum += __shfl_xor(vsum, 8, 64);
            if (nq == 0) neg_part[ch * NN + rowW + rs * 16 + q * 4 + rr] = vsum;
        }
}

// ---- pass 2: per-class MFMA over member rows + fused finalize ----
__global__ __launch_bounds__(256) void k_loss(
        const unsigned short* __restrict__ nf,
        const int* __restrict__ counts, const int* __restrict__ offsets,
        const int* __restrict__ classIdx,
        const float* __restrict__ neg_part,
        float* __restrict__ total, unsigned* __restrict__ done,
        float* __restrict__ out) {
    __shared__ __attribute__((aligned(16))) unsigned short s_feat[MAXR * 128]; // 48 KB
    __shared__ int s_rows[MAXR];
    __shared__ float s_ns[MAXR];
    __shared__ float red[4];

    int c = blockIdx.x;
    int m = counts[c], off = offsets[c];
    int twoM = 2 * m; if (twoM > MAXR) twoM = MAXR;
    int tid = threadIdx.x, wave = tid >> 6, lane = tid & 63;
    int q = lane >> 4, nq = lane & 15;

    for (int r = tid; r < twoM; r += 256) {
        int b = classIdx[off + (r < m ? r : r - m)];
        int row = (r < m) ? b : b + BATCH;
        s_rows[r] = row;
        float ns = 0.0f;
        #pragma unroll
        for (int chp = 0; chp < NCHUNK; ++chp) ns += neg_part[chp * NN + row];
        s_ns[r] = ns;
    }
    __syncthreads();    // s_rows ready before gather staging

    int ntile = (twoM + 63) >> 6;            // 1..3
    int nchunk = ntile * 64 * 16;
    // gather-stage rows (clamped: r>=twoM duplicates last row; masked later)
    for (int widx = wave; widx * 64 < nchunk; widx += 4) {
        int chunkIdx = widx * 64 + lane;
        int r = chunkIdx >> 4, cS = chunkIdx & 15;
        int cG = cS ^ (r & 15);
        int rc = r < twoM ? r : twoM - 1;
        const unsigned short* gp = nf + (size_t)s_rows[rc] * DD + cG * 8;
        unsigned short* lp = s_feat + (size_t)widx * 512;
        __builtin_amdgcn_global_load_lds(
            (const __attribute__((address_space(1))) void*)gp,
            (__attribute__((address_space(3))) void*)lp, 16, 0, 0);
    }
    __syncthreads();

    const char* sB = (const char*)s_feat;
    float partial = 0.0f;
    int npairs = ntile * ntile;
    for (int pp = wave; pp < npairs; pp += 4) {
        int ti = pp / ntile, tj = pp - ti * ntile;
        bf16x8 aF[4][4];
        #pragma unroll
        for (int rs = 0; rs < 4; ++rs) {
            int rA = ti * 64 + rs * 16 + nq;
            #pragma unroll
            for (int s = 0; s < 4; ++s) {
                int slot = rA * 16 + ((s * 4 + q) ^ nq);
                aF[rs][s] = *(const bf16x8*)(sB + slot * 16);
            }
        }
        f32x4 acc[4][4];
        #pragma unroll
        for (int rs = 0; rs < 4; ++rs)
            #pragma unroll
            for (int cs = 0; cs < 4; ++cs) acc[rs][cs] = (f32x4){0.f, 0.f, 0.f, 0.f};
        #pragma unroll
        for (int s = 0; s < 4; ++s) {
            bf16x8 bF[4];
            #pragma unroll
            for (int cs = 0; cs < 4; ++cs) {
                int rB = tj * 64 + cs * 16 + nq;
                int slot = rB * 16 + ((s * 4 + q) ^ nq);
                bF[cs] = *(const bf16x8*)(sB + slot * 16);
            }
            #pragma unroll
            for (int rs = 0; rs < 4; ++rs)
                #pragma unroll
                for (int cs = 0; cs < 4; ++cs)
                    acc[rs][cs] = __builtin_amdgcn_mfma_f32_16x16x32_bf16(
                        aF[rs][s], bF[cs], acc[rs][cs], 0, 0, 0);
        }
        #pragma unroll
        for (int cs = 0; cs < 4; ++cs) {
            int qq = tj * 64 + cs * 16 + nq;
            float ns = s_ns[qq < twoM ? qq : 0];
            #pragma unroll
            for (int rs = 0; rs < 4; ++rs)
                #pragma unroll
                for (int rr = 0; rr < 4; ++rr) {
                    int p = ti * 64 + rs * 16 + q * 4 + rr;
                    bool valid = (p < twoM) && (qq < twoM) && (p != qq);
                    float logit = acc[rs][cs][rr] * SCALE;
                    float term = logit - __logf(ns + __expf(logit));
                    partial += valid ? term : 0.0f;
                }
        }
    }
    #pragma unroll
    for (int mm = 32; mm >= 1; mm >>= 1) partial += __shfl_xor(partial, mm, 64);
    if (lane == 0) red[wave] = partial;
    __syncthreads();
    if (tid == 0) {
        atomicAdd(total, red[0] + red[1] + red[2] + red[3]);
        __threadfence();
        unsigned prev = __hip_atomic_fetch_add(done, 1u, __ATOMIC_ACQ_REL,
                                               __HIP_MEMORY_SCOPE_AGENT);
        if (prev == (unsigned)(NCLS - 1)) {
            float tot = __hip_atomic_load(total, __ATOMIC_ACQUIRE,
                                          __HIP_MEMORY_SCOPE_AGENT);
            out[0] = -tot * (1.0f / (float)NN);
        }
    }
}

extern "C" void kernel_launch(void* const* d_in, const int* in_sizes, int n_in,
                              void* d_out, int out_size, void* d_ws, size_t ws_size,
                              hipStream_t stream) {
    const float* feat = (const float*)d_in[0];
    const int* labels = (const int*)d_in[1];
    unsigned short* nf = (unsigned short*)d_ws;
    float* neg_part = (float*)((char*)d_ws + (size_t)NN * DD * sizeof(unsigned short));
    float* total    = neg_part + NCHUNK * NN; // 1
    unsigned* done  = (unsigned*)(total + 1); // 1
    int* counts     = (int*)(done + 1);       // 100
    int* offsets    = counts + NCLS;          // 101
    int* classIdx   = offsets + NCLS + 1;     // 4096
    float* out = (float*)d_out;

    hipLaunchKernelGGL(k_norm_bucket, dim3(NN / 4 + 1), dim3(256), 0, stream,
                       feat, nf, (unsigned*)total, labels, counts, offsets, classIdx);
    hipLaunchKernelGGL(k_negsum, dim3(64 * NCHUNK), dim3(256), 0, stream, nf, labels, neg_part);
    hipLaunchKernelGGL(k_loss, dim3(NCLS), dim3(256), 0, stream,
                       nf, counts, offsets, classIdx, neg_part, total, done, out);
}